// Round 1
// baseline (2644.549 us; speedup 1.0000x reference)
//
#include <hip/hip_runtime.h>

#define NSEG   800
#define BATCH  256
#define NFREQ  51
#define NPER   100
#define NELEM  (BATCH*NFREQ)   // 13056
#define NSAMP  80000

// ---------------- compile-time twiddles (double Taylor, exact to fp32) ----------------
constexpr double TCPI  = 3.14159265358979323846264338327950288;
constexpr double TC2PI = 6.28318530717958647692528676655900577;

constexpr double taylor_cos(double y) {   // |y| <= pi
    double y2 = y * y, term = 1.0, sum = 1.0;
    for (int j = 1; j <= 26; ++j) { term *= -y2 / (double)((2*j-1)*(2*j)); sum += term; }
    return sum;
}
constexpr double cos_k(int k) {           // cos(2*pi*k/100)
    return -taylor_cos(TC2PI * (double)k / 100.0 - TCPI);
}
constexpr double sin_k(int k) {           // sin(2*pi*k/100)
    return (k >= 50) ? -taylor_cos(TC2PI * (double)(k - 50) / 100.0 - TCPI * 0.5)
                     :  taylor_cos(TC2PI * (double)k        / 100.0 - TCPI * 0.5);
}

struct TwTab {
    float c[100], s[100], w[100];
    constexpr TwTab() : c{}, s{}, w{} {
        for (int k = 0; k < 100; ++k) {
            c[k] = (float)cos_k(k);
            s[k] = (float)sin_k(k);
            w[k] = (float)(1.0 - cos_k(k));   // hann(periodic)*2 = 1 - cos(2*pi*n/100)
        }
    }
};
constexpr TwTab TW{};

// ---------------- kernel 1: per-(array,segment) PSD -> log -> normalize -> accumulate ----------------
// ws layout (floats): [0,13056) sumF | [13056,26112) sumR | [26112,27712) sa per (a,seg)
__global__ __launch_bounds__(256, 3) void psd_seg_kernel(
    const float* __restrict__ fake, const float* __restrict__ real,
    float* __restrict__ sumF, float* __restrict__ sumR, float* __restrict__ saArr)
{
    __shared__ float ldsL[NELEM];       // 52224 B
    __shared__ float ldsmn[BATCH];      // 1024 B
    __shared__ float ldsinv[BATCH];     // 1024 B
    __shared__ float ldsred[4];

    const int bx = blockIdx.x;
    const int a  = bx / NSEG;           // 0 = fake, 1 = real
    const int s  = bx - a * NSEG;
    const int t  = threadIdx.x;

    const float* __restrict__ src = a ? real : fake;
    const float4* __restrict__ rowp =
        (const float4*)(src + (size_t)t * NSAMP + (size_t)s * NPER);

    // ---- load row (25 aligned float4), clamp + window with compile-time constants ----
    float x[NPER];
    #pragma unroll
    for (int q = 0; q < 25; ++q) {
        float4 v = rowp[q];
        x[4*q+0] = fmaxf(v.x, 1e-6f) * TW.w[4*q+0];
        x[4*q+1] = fmaxf(v.y, 1e-6f) * TW.w[4*q+1];
        x[4*q+2] = fmaxf(v.z, 1e-6f) * TW.w[4*q+2];
        x[4*q+3] = fmaxf(v.w, 1e-6f) * TW.w[4*q+3];
    }

    // ---- in-place even/odd butterfly: x[n] := x[n]+x[100-n], x[100-n] := x[n]-x[100-n] ----
    #pragma unroll
    for (int n = 1; n <= 49; ++n) {
        float tn = x[n], tm = x[NPER - n];
        x[n]        = tn + tm;
        x[NPER - n] = tn - tm;
    }
    const float x0 = x[0], x50 = x[50];

    // ---- direct DFT, twiddles as instruction literals; PSD -> signed clamp log -> LDS ----
    #pragma unroll
    for (int f = 0; f < NFREQ; ++f) {
        float re = x0 + ((f & 1) ? -x50 : x50);
        float im = 0.0f;
        #pragma unroll
        for (int n = 1; n <= 49; ++n) {
            re = fmaf(x[n],        TW.c[(f*n) % 100], re);
            im = fmaf(x[NPER - n], TW.s[(f*n) % 100], im);
        }
        float p  = fmaf(re, re, im * im);
        p        = fmaxf(p, 1e-38f);
        float lx = __logf(p);
        float al = fmaxf(fabsf(lx), 1e-6f);
        float L  = (lx > 0.0f) ? al : ((lx < 0.0f) ? -al : 0.0f);
        ldsL[t * NFREQ + f] = L;
    }
    __syncthreads();

    // ---- strided group min/max: group c holds flat indices r*256 + c, r = 0..50 ----
    {
        float mn = 1e30f, mx = -1e30f;
        #pragma unroll
        for (int r = 0; r < NFREQ; ++r) {
            float vL = ldsL[r * BATCH + t];
            mn = fminf(mn, vL);
            mx = fmaxf(mx, vL);
        }
        ldsmn[t]  = mn;
        ldsinv[t] = 1.0f / (mx - mn);
    }
    __syncthreads();

    // ---- normalize, accumulate ssq and element-wise sums ----
    float* __restrict__ sumX = a ? sumR : sumF;
    float ssq = 0.0f;
    #pragma unroll
    for (int f = 0; f < NFREQ; ++f) {
        int   e  = t * NFREQ + f;
        int   cc = e & (BATCH - 1);
        float F  = (ldsL[e] - ldsmn[cc]) * ldsinv[cc];
        ssq = fmaf(F, F, ssq);
        unsafeAtomicAdd(&sumX[e], F);   // HW global_atomic_add_f32
    }

    // ---- block-reduce ssq -> saArr[bx] ----
    #pragma unroll
    for (int off = 32; off; off >>= 1) ssq += __shfl_down(ssq, off, 64);
    if ((t & 63) == 0) ldsred[t >> 6] = ssq;
    __syncthreads();
    if (t == 0) saArr[bx] = ldsred[0] + ldsred[1] + ldsred[2] + ldsred[3];
}

// ---------------- kernel 2: final reduction in double ----------------
__global__ void finalize_kernel(const float* __restrict__ ws, float* __restrict__ out)
{
    __shared__ double red[4][4];
    const int t = threadIdx.x;

    double dot = 0.0, ff = 0.0, sF = 0.0, sR = 0.0;
    for (int e = t; e < NELEM; e += 256) {
        double fv = (double)ws[e];
        double rv = (double)ws[NELEM + e];
        dot += fv * rv;
        ff  += fv * fv;
    }
    for (int i = t; i < NSEG; i += 256) {
        sF += (double)ws[2 * NELEM + i];
        sR += (double)ws[2 * NELEM + NSEG + i];
    }
    #pragma unroll
    for (int off = 32; off; off >>= 1) {
        dot += __shfl_down(dot, off, 64);
        ff  += __shfl_down(ff,  off, 64);
        sF  += __shfl_down(sF,  off, 64);
        sR  += __shfl_down(sR,  off, 64);
    }
    const int w = t >> 6;
    if ((t & 63) == 0) { red[0][w] = dot; red[1][w] = ff; red[2][w] = sF; red[3][w] = sR; }
    __syncthreads();
    if (t == 0) {
        double d  = red[0][0] + red[0][1] + red[0][2] + red[0][3];
        double f2 = red[1][0] + red[1][1] + red[1][2] + red[1][3];
        double SF = red[2][0] + red[2][1] + red[2][2] + red[2][3];
        double SR = red[3][0] + red[3][1] + red[3][2] + red[3][3];

        const double n    = (double)NELEM;        // 13056
        const double nseg = (double)NSEG;         // 800
        const double m    = nseg * (nseg - 1.0) * 0.5;   // 319600

        double psd_loss = (SF / nseg + SR / nseg - 2.0 * d / (nseg * nseg)) / n;
        double selfl    = (nseg * SF - f2) / (n * m);

        out[0] = (float)psd_loss;
        out[1] = (float)selfl;
    }
}

extern "C" void kernel_launch(void* const* d_in, const int* in_sizes, int n_in,
                              void* d_out, int out_size, void* d_ws, size_t ws_size,
                              hipStream_t stream) {
    const float* fake = (const float*)d_in[0];
    const float* real = (const float*)d_in[1];
    float* ws  = (float*)d_ws;
    float* out = (float*)d_out;

    // zero the accumulators (ws is poisoned 0xAA before every launch)
    hipMemsetAsync(d_ws, 0, (size_t)(2 * NELEM + 2 * NSEG) * sizeof(float), stream);

    psd_seg_kernel<<<2 * NSEG, 256, 0, stream>>>(fake, real, ws, ws + NELEM, ws + 2 * NELEM);
    finalize_kernel<<<1, 256, 0, stream>>>(ws, out);
}

// Round 2
// 562.192 us; speedup vs baseline: 4.7040x; 4.7040x over previous
//
#include <hip/hip_runtime.h>

#define NSEG   800
#define BATCH  256
#define NFREQ  51
#define NPER   100
#define NELEM  (BATCH*NFREQ)      // 13056
#define NSAMP  80000
#define NF4ROW 25                 // float4 per 100-sample row segment
#define NF4HALF (128*NF4ROW)      // 3200 float4 per half tile
#define NF4EL  (NELEM/4)          // 3264 float4 per F vector
#define NJ     16                 // K2 column-sum split

// ---------------- compile-time twiddles (double Taylor, exact to fp32) ----------------
constexpr double TCPI  = 3.14159265358979323846264338327950288;
constexpr double TC2PI = 6.28318530717958647692528676655900577;

constexpr double taylor_cos(double y) {   // |y| <= pi
    double y2 = y * y, term = 1.0, sum = 1.0;
    for (int j = 1; j <= 26; ++j) { term *= -y2 / (double)((2*j-1)*(2*j)); sum += term; }
    return sum;
}
constexpr double cos_k(int k) {           // cos(2*pi*k/100)
    return -taylor_cos(TC2PI * (double)k / 100.0 - TCPI);
}
constexpr double sin_k(int k) {           // sin(2*pi*k/100)
    return (k >= 50) ? -taylor_cos(TC2PI * (double)(k - 50) / 100.0 - TCPI * 0.5)
                     :  taylor_cos(TC2PI * (double)k        / 100.0 - TCPI * 0.5);
}

struct TwTab {
    float c[100], s[100], w[100];
    constexpr TwTab() : c{}, s{}, w{} {
        for (int k = 0; k < 100; ++k) {
            c[k] = (float)cos_k(k);
            s[k] = (float)sin_k(k);
            w[k] = (float)(1.0 - cos_k(k));   // hann(periodic)*2
        }
    }
};
constexpr TwTab TW{};

// ---------------- K1: per-(array,segment) PSD -> log -> normalize ----------------
// DUMP=true : write normalized F vector (13056 floats) to part[bx], no atomics.
// DUMP=false: atomic-accumulate into sumF/sumR at part (ws too small fallback).
template<bool DUMP>
__global__ __launch_bounds__(256, 2) void psd_seg_kernel(
    const float* __restrict__ fake, const float* __restrict__ real,
    float* __restrict__ part, float* __restrict__ saArr)
{
    __shared__ float ldsL[NELEM];       // 52224 B; doubles as 51200-B staging buffer
    __shared__ float ldsmn[BATCH];
    __shared__ float ldsinv[BATCH];
    __shared__ float ldsred[4];

    const int bx = blockIdx.x;
    const int a  = bx >= NSEG;          // 0 = fake, 1 = real
    const int s  = a ? bx - NSEG : bx;
    const int t  = threadIdx.x;

    const float4* __restrict__ src4 = (const float4*)(a ? real : fake);
    float4* lds4 = (float4*)ldsL;

    float x[NPER];

    // ---- coalesced two-phase staging: rows [0,128) then [128,256) ----
    #pragma unroll
    for (int half = 0; half < 2; ++half) {
        for (int j = t; j < NF4HALF; j += 256) {
            int r = j / NF4ROW;                       // 0..127 (25-lane runs of 400 B)
            int q = j - r * NF4ROW;
            lds4[j] = src4[(size_t)(half * 128 + r) * 20000 + s * NF4ROW + q];
        }
        __syncthreads();
        if ((t >> 7) == half) {                        // own row staged this phase
            const int rr = t & 127;
            #pragma unroll
            for (int q = 0; q < NF4ROW; ++q) {         // stride 25 f4 -> conflict-free b128
                float4 v = lds4[rr * NF4ROW + q];
                x[4*q+0] = fmaxf(v.x, 1e-6f) * TW.w[4*q+0];
                x[4*q+1] = fmaxf(v.y, 1e-6f) * TW.w[4*q+1];
                x[4*q+2] = fmaxf(v.z, 1e-6f) * TW.w[4*q+2];
                x[4*q+3] = fmaxf(v.w, 1e-6f) * TW.w[4*q+3];
            }
        }
        __syncthreads();
    }

    // ---- even/odd butterfly ----
    #pragma unroll
    for (int n = 1; n <= 49; ++n) {
        float tn = x[n], tm = x[NPER - n];
        x[n]        = tn + tm;
        x[NPER - n] = tn - tm;
    }
    const float x0 = x[0], x50 = x[50];

    // ---- direct DFT with literal twiddles; PSD -> signed clamp log -> LDS ----
    #pragma unroll
    for (int f = 0; f < NFREQ; ++f) {
        float re = x0 + ((f & 1) ? -x50 : x50);
        float im = 0.0f;
        #pragma unroll
        for (int n = 1; n <= 49; ++n) {
            re = fmaf(x[n],        TW.c[(f*n) % 100], re);
            im = fmaf(x[NPER - n], TW.s[(f*n) % 100], im);
        }
        float p  = fmaf(re, re, im * im);
        p        = fmaxf(p, 1e-38f);
        float lx = __logf(p);
        float al = fmaxf(fabsf(lx), 1e-6f);
        float L  = (lx > 0.0f) ? al : ((lx < 0.0f) ? -al : 0.0f);
        ldsL[t * NFREQ + f] = L;
    }
    __syncthreads();

    // ---- group min/max: group c = flat indices r*256 + c ----
    {
        float mn = 1e30f, mx = -1e30f;
        #pragma unroll
        for (int r = 0; r < NFREQ; ++r) {
            float vL = ldsL[r * BATCH + t];
            mn = fminf(mn, vL);
            mx = fmaxf(mx, vL);
        }
        ldsmn[t]  = mn;
        ldsinv[t] = 1.0f / (mx - mn);
    }
    __syncthreads();

    // ---- normalize in place, accumulate ssq ----
    float ssq = 0.0f;
    #pragma unroll
    for (int f = 0; f < NFREQ; ++f) {
        int   e  = t * NFREQ + f;
        int   cc = e & (BATCH - 1);
        float F  = (ldsL[e] - ldsmn[cc]) * ldsinv[cc];
        ssq = fmaf(F, F, ssq);
        if (DUMP) ldsL[e] = F;
        else      unsafeAtomicAdd(&part[a * NELEM + e], F);
    }

    if (DUMP) {
        __syncthreads();
        float4* __restrict__ dst = (float4*)part + (size_t)bx * NF4EL;
        for (int j = t; j < NF4EL; j += 256) dst[j] = lds4[j];   // coalesced dump
    }

    // ---- block-reduce ssq ----
    #pragma unroll
    for (int off = 32; off; off >>= 1) ssq += __shfl_down(ssq, off, 64);
    if ((t & 63) == 0) ldsred[t >> 6] = ssq;
    __syncthreads();
    if (t == 0) saArr[bx] = ldsred[0] + ldsred[1] + ldsred[2] + ldsred[3];
}

// ---------------- K2: column-sum partials over 50-block slabs ----------------
__global__ void reduce_part_kernel(const float* __restrict__ part, float* __restrict__ pb)
{
    const int e = blockIdx.x * 256 + threadIdx.x;   // < 13056
    const int j = blockIdx.y;                        // < NJ
    const float* __restrict__ pF = part + (size_t)(j * (NSEG / NJ)) * NELEM + e;
    const float* __restrict__ pR = part + (size_t)(NSEG + j * (NSEG / NJ)) * NELEM + e;
    float sF = 0.0f, sR = 0.0f;
    #pragma unroll 5
    for (int i = 0; i < NSEG / NJ; ++i) {
        sF += pF[(size_t)i * NELEM];
        sR += pR[(size_t)i * NELEM];
    }
    pb[(size_t)(2 * j + 0) * NELEM + e] = sF;
    pb[(size_t)(2 * j + 1) * NELEM + e] = sR;
}

// ---------------- double block-reduce helper ----------------
__device__ __forceinline__ void block_reduce2_store(double d, double f2, double* dst,
                                                    double (*red)[4], int t)
{
    #pragma unroll
    for (int off = 32; off; off >>= 1) {
        d  += __shfl_down(d,  off, 64);
        f2 += __shfl_down(f2, off, 64);
    }
    if ((t & 63) == 0) { red[0][t >> 6] = d; red[1][t >> 6] = f2; }
    __syncthreads();
    if (t == 0) {
        dst[0] = red[0][0] + red[0][1] + red[0][2] + red[0][3];
        dst[1] = red[1][0] + red[1][1] + red[1][2] + red[1][3];
    }
}

// ---------------- K3: finish column sums, form per-e dot/ff, reduce per block ----------------
__global__ void dot_kernel(const float* __restrict__ pb, double* __restrict__ k3out)
{
    __shared__ double red[2][4];
    const int t = threadIdx.x;
    const int e = blockIdx.x * 256 + t;
    float sF = 0.0f, sR = 0.0f;
    #pragma unroll
    for (int j = 0; j < NJ; ++j) {
        sF += pb[(size_t)(2 * j + 0) * NELEM + e];
        sR += pb[(size_t)(2 * j + 1) * NELEM + e];
    }
    double d  = (double)sF * (double)sR;
    double f2 = (double)sF * (double)sF;
    block_reduce2_store(d, f2, k3out + 2 * blockIdx.x, red, t);
}

// K3 fallback: sums already in sumF/sumR (atomic path)
__global__ void dot_direct_kernel(const float* __restrict__ sums, double* __restrict__ k3out)
{
    __shared__ double red[2][4];
    const int t = threadIdx.x;
    const int e = blockIdx.x * 256 + t;
    double sF = (double)sums[e], sR = (double)sums[NELEM + e];
    block_reduce2_store(sF * sR, sF * sF, k3out + 2 * blockIdx.x, red, t);
}

// ---------------- K4: final combine in double ----------------
__global__ void final_kernel(const double* __restrict__ k3out, const float* __restrict__ saArr,
                             float* __restrict__ out)
{
    __shared__ double red[4][4];
    const int t = threadIdx.x;
    double d = 0.0, f2 = 0.0, sf = 0.0, sr = 0.0;
    if (t < NFREQ) { d = k3out[2 * t]; f2 = k3out[2 * t + 1]; }
    for (int i = t; i < NSEG; i += 256) {
        sf += (double)saArr[i];
        sr += (double)saArr[NSEG + i];
    }
    #pragma unroll
    for (int off = 32; off; off >>= 1) {
        d  += __shfl_down(d,  off, 64);
        f2 += __shfl_down(f2, off, 64);
        sf += __shfl_down(sf, off, 64);
        sr += __shfl_down(sr, off, 64);
    }
    const int w = t >> 6;
    if ((t & 63) == 0) { red[0][w] = d; red[1][w] = f2; red[2][w] = sf; red[3][w] = sr; }
    __syncthreads();
    if (t == 0) {
        double D  = red[0][0] + red[0][1] + red[0][2] + red[0][3];
        double FF = red[1][0] + red[1][1] + red[1][2] + red[1][3];
        double SF = red[2][0] + red[2][1] + red[2][2] + red[2][3];
        double SR = red[3][0] + red[3][1] + red[3][2] + red[3][3];

        const double n    = (double)NELEM;
        const double nseg = (double)NSEG;
        const double m    = nseg * (nseg - 1.0) * 0.5;

        out[0] = (float)((SF / nseg + SR / nseg - 2.0 * D / (nseg * nseg)) / n);
        out[1] = (float)((nseg * SF - FF) / (n * m));
    }
}

extern "C" void kernel_launch(void* const* d_in, const int* in_sizes, int n_in,
                              void* d_out, int out_size, void* d_ws, size_t ws_size,
                              hipStream_t stream) {
    const float* fake = (const float*)d_in[0];
    const float* real = (const float*)d_in[1];
    float* ws  = (float*)d_ws;
    float* out = (float*)d_out;

    // Path-A (no atomics) ws layout, floats:
    //   [0, 1600*13056)          per-block F dumps
    //   [PART_FL, +1600)         per-block ssq
    //   [SA_FL+1600, +2*NJ*13056) K2 column-sum slabs
    //   then 8B-aligned: 51*2 doubles (K3 out)
    const size_t PART_FL = (size_t)2 * NSEG * NELEM;       // 20,889,600
    const size_t SA_FL   = PART_FL;                        // ssq at PART_FL
    const size_t PB_FL   = PART_FL + 1600;
    const size_t K3_BYTE = (PB_FL + (size_t)2 * NJ * NELEM) * 4;   // 8B-aligned
    const size_t NEED_A  = K3_BYTE + 2 * NFREQ * sizeof(double);

    if (ws_size >= NEED_A) {
        float*  sa  = ws + SA_FL;
        float*  pb  = ws + PB_FL;
        double* k3  = (double*)((char*)d_ws + K3_BYTE);
        psd_seg_kernel<true><<<2 * NSEG, 256, 0, stream>>>(fake, real, ws, sa);
        reduce_part_kernel<<<dim3(NFREQ, NJ), 256, 0, stream>>>(ws, pb);
        dot_kernel<<<NFREQ, 256, 0, stream>>>(pb, k3);
        final_kernel<<<1, 256, 0, stream>>>(k3, sa, out);
    } else {
        // Fallback: atomic accumulation (small ws). sumF|sumR|sa|k3
        float*  sa = ws + 2 * NELEM;
        double* k3 = (double*)((char*)d_ws + ((2 * NELEM + 1600) * 4));
        hipMemsetAsync(d_ws, 0, (size_t)2 * NELEM * sizeof(float), stream);
        psd_seg_kernel<false><<<2 * NSEG, 256, 0, stream>>>(fake, real, ws, sa);
        dot_direct_kernel<<<NFREQ, 256, 0, stream>>>(ws, k3);
        final_kernel<<<1, 256, 0, stream>>>(k3, sa, out);
    }
}

// Round 3
// 492.787 us; speedup vs baseline: 5.3665x; 1.1408x over previous
//
#include <hip/hip_runtime.h>

#define NSEG   800
#define BATCH  256
#define NFREQ  51
#define NELEM  (BATCH*NFREQ)      // 13056
#define NSAMP  80000
#define GPB    2                  // segments per block
#define NBLK   (2*NSEG/GPB)       // 800 K1 blocks
#define GRP    (NSEG/GPB)         // 400 per array
#define NJ     8                  // reduce split
#define GPJ    (GRP/NJ)           // 50

// ---------------- compile-time trig (double Taylor, exact to fp32) ----------------
constexpr double TCPI  = 3.14159265358979323846264338327950288;
constexpr double TC2PI = 6.28318530717958647692528676655900577;

constexpr double taylor_cos(double y) {   // |y| <= pi
    double y2 = y * y, term = 1.0, sum = 1.0;
    for (int j = 1; j <= 26; ++j) { term *= -y2 / (double)((2*j-1)*(2*j)); sum += term; }
    return sum;
}
constexpr double cos_k(int k) {           // cos(2*pi*k/100)
    return -taylor_cos(TC2PI * (double)(k % 100) / 100.0 - TCPI);
}
constexpr double sin_k(int k) {
    int kk = k % 100;
    return (kk >= 50) ? -taylor_cos(TC2PI * (double)(kk - 50) / 100.0 - TCPI * 0.5)
                      :  taylor_cos(TC2PI * (double)kk        / 100.0 - TCPI * 0.5);
}

struct Tabs { float c[50]; float s[50]; float wA[50]; float wB[51]; };
constexpr Tabs make_tabs() {
    Tabs t{};
    for (int k = 0; k < 50; ++k) {
        t.c[k]  = (float)cos_k(k);
        t.s[k]  = (float)sin_k(k);
        int smp = (k < 25) ? k : k + 50;                 // phase-A sample map
        t.wA[k] = (float)(1.0 - cos_k(smp));             // hann(periodic)*2
    }
    for (int q = 0; q < 51; ++q) t.wB[q] = (float)(1.0 - cos_k(q + 25));
    return t;
}
__device__ const Tabs d_tabs = make_tabs();

// One outer-n DFT step: rotation twiddles, f<->50-f mirror amortization.
__device__ __forceinline__ void dft_step(float xn, float xm, float sgn,
                                         float cd, float sd,
                                         float (&re)[NFREQ], float (&im)[NFREQ])
{
    float u  = xn + xm, v = xn - xm;
    float us = sgn * u;
    float vs = -(sgn * v);
    float c = 1.0f, s = 0.0f;
    re[0]  += u;        // f=0:  cos=1
    re[50] += us;       // f=50: (-1)^n
    #pragma unroll
    for (int fp = 1; fp <= 25; ++fp) {
        float nc = fmaf(-s, sd, c * cd);
        float ns = fmaf( c, sd, s * cd);
        c = nc; s = ns;
        re[fp] = fmaf(u, c, re[fp]);
        im[fp] = fmaf(v, s, im[fp]);
        if (fp < 25) {
            re[50 - fp] = fmaf(us, c, re[50 - fp]);
            im[50 - fp] = fmaf(vs, s, im[50 - fp]);
        }
    }
}

// ---------------- K1: 2 segments/block, rolled-n DFT, reg-accumulated sums ----------------
// ws: part[800][13056] | saArr[800] | pb[2*NJ][13056] | k2out[51][2] (double)
__global__ __launch_bounds__(256, 2) void psd_seg_kernel(
    const float* __restrict__ fake, const float* __restrict__ real,
    float* __restrict__ part, float* __restrict__ saArr)
{
    __shared__ float xs[NELEM];        // 52224 B: x-stage, then L-buffer, then dump-stage
    __shared__ float ldsmn[BATCH];
    __shared__ float ldsinv[BATCH];
    __shared__ float ldsred[4];

    const int bx = blockIdx.x;
    const int a  = bx >= GRP;
    const int g  = a ? bx - GRP : bx;
    const int t  = threadIdx.x;
    const float* __restrict__ src = a ? real : fake;

    float sumAcc[NFREQ];
    #pragma unroll
    for (int f = 0; f < NFREQ; ++f) sumAcc[f] = 0.0f;
    float ssq = 0.0f;

    for (int si = 0; si < GPB; ++si) {
        const int s = GPB * g + si;
        float re[NFREQ], im[NFREQ];
        #pragma unroll
        for (int f = 0; f < NFREQ; ++f) { re[f] = 0.0f; im[f] = 0.0f; }

        // ---- stage A: samples {0..24}u{75..99} -> xs[row*51+q], q=0..49
        for (int k = t; k < 12800; k += 256) {
            int row = k / 50, q = k - row * 50;
            int smp = (q < 25) ? q : q + 50;
            float raw = src[(size_t)row * NSAMP + s * 100 + smp];
            xs[row * 51 + q] = fmaxf(raw, 1e-6f) * d_tabs.wA[q];
        }
        __syncthreads();
        // ---- DFT phase A: n=1..24  (xn at q=n, xm=x[100-n] at q=50-n)
        {
            const float* lx = xs + t * 51;
            float sgn = -1.0f;                       // (-1)^1
            #pragma unroll 2
            for (int n = 1; n <= 24; ++n) {
                dft_step(lx[n], lx[50 - n], sgn, d_tabs.c[n], d_tabs.s[n], re, im);
                sgn = -sgn;
            }
        }
        __syncthreads();
        // ---- stage B: samples {25..75} -> xs[row*51+q], q=0..50
        for (int k = t; k < NELEM; k += 256) {
            int row = k / 51, q = k - row * 51;
            float raw = src[(size_t)row * NSAMP + s * 100 + 25 + q];
            xs[row * 51 + q] = fmaxf(raw, 1e-6f) * d_tabs.wB[q];
        }
        __syncthreads();
        // ---- DFT phase B: n=25..49 (xn at q=n-25, xm=x[100-n] at q=75-n); x50 at q=25
        float x50;
        {
            const float* lx = xs + t * 51;
            float sgn = -1.0f;                       // (-1)^25
            #pragma unroll 2
            for (int n = 25; n <= 49; ++n) {
                dft_step(lx[n - 25], lx[75 - n], sgn, d_tabs.c[n], d_tabs.s[n], re, im);
                sgn = -sgn;
            }
            x50 = lx[25];
        }
        __syncthreads();
        // ---- PSD -> signed clamp log -> xs (reused as L buffer), e = t*51+f
        #pragma unroll
        for (int f = 0; f < NFREQ; ++f) {
            float rr = re[f] + ((f & 1) ? -x50 : x50);
            float p  = fmaf(rr, rr, im[f] * im[f]);
            p        = fmaxf(p, 1e-38f);
            float lv = __logf(p);
            float al = fmaxf(fabsf(lv), 1e-6f);
            xs[t * 51 + f] = (lv > 0.0f) ? al : ((lv < 0.0f) ? -al : 0.0f);
        }
        __syncthreads();
        // ---- group min/max: group c=t holds flat indices r*256+t
        {
            float mn = 1e30f, mx = -1e30f;
            #pragma unroll
            for (int r = 0; r < NFREQ; ++r) {
                float v = xs[r * BATCH + t];
                mn = fminf(mn, v);
                mx = fmaxf(mx, v);
            }
            ldsmn[t]  = mn;
            ldsinv[t] = 1.0f / (mx - mn);
        }
        __syncthreads();
        // ---- fold normalized F into register accumulators
        #pragma unroll
        for (int f = 0; f < NFREQ; ++f) {
            int   e  = t * 51 + f;
            int   cc = e & (BATCH - 1);
            float F  = (xs[e] - ldsmn[cc]) * ldsinv[cc];
            ssq = fmaf(F, F, ssq);
            sumAcc[f] += F;
        }
        __syncthreads();
    }

    // ---- dump per-block element sums (coalesced via LDS) ----
    #pragma unroll
    for (int f = 0; f < NFREQ; ++f) xs[t * 51 + f] = sumAcc[f];
    __syncthreads();
    {
        float4* __restrict__ dst = (float4*)(part + (size_t)bx * NELEM);
        const float4* l4 = (const float4*)xs;
        for (int j = t; j < NELEM / 4; j += 256) dst[j] = l4[j];
    }

    // ---- block-reduce ssq ----
    #pragma unroll
    for (int off = 32; off; off >>= 1) ssq += __shfl_down(ssq, off, 64);
    if ((t & 63) == 0) ldsred[t >> 6] = ssq;
    __syncthreads();
    if (t == 0) saArr[bx] = ldsred[0] + ldsred[1] + ldsred[2] + ldsred[3];
}

// ---------------- K2a: partial column sums over 50-block slabs ----------------
__global__ void reduce_part_kernel(const float* __restrict__ part, float* __restrict__ pb)
{
    const int e = blockIdx.x * 256 + threadIdx.x;   // < 13056
    const int j = blockIdx.y;                        // < NJ
    const float* __restrict__ pF = part + (size_t)(j * GPJ) * NELEM + e;
    const float* __restrict__ pR = part + (size_t)(GRP + j * GPJ) * NELEM + e;
    float sF = 0.0f, sR = 0.0f;
    #pragma unroll 5
    for (int i = 0; i < GPJ; ++i) {
        sF += pF[(size_t)i * NELEM];
        sR += pR[(size_t)i * NELEM];
    }
    pb[(size_t)(2 * j + 0) * NELEM + e] = sF;
    pb[(size_t)(2 * j + 1) * NELEM + e] = sR;
}

// ---------------- K2b: finish sums, per-e dot/ff, block reduce ----------------
__global__ void dot_kernel(const float* __restrict__ pb, double* __restrict__ k2out)
{
    __shared__ double red[2][4];
    const int t = threadIdx.x;
    const int e = blockIdx.x * 256 + t;
    float sF = 0.0f, sR = 0.0f;
    #pragma unroll
    for (int j = 0; j < NJ; ++j) {
        sF += pb[(size_t)(2 * j + 0) * NELEM + e];
        sR += pb[(size_t)(2 * j + 1) * NELEM + e];
    }
    double d  = (double)sF * (double)sR;
    double f2 = (double)sF * (double)sF;
    #pragma unroll
    for (int off = 32; off; off >>= 1) {
        d  += __shfl_down(d,  off, 64);
        f2 += __shfl_down(f2, off, 64);
    }
    if ((t & 63) == 0) { red[0][t >> 6] = d; red[1][t >> 6] = f2; }
    __syncthreads();
    if (t == 0) {
        k2out[2 * blockIdx.x + 0] = red[0][0] + red[0][1] + red[0][2] + red[0][3];
        k2out[2 * blockIdx.x + 1] = red[1][0] + red[1][1] + red[1][2] + red[1][3];
    }
}

// ---------------- K3: final combine in double ----------------
__global__ void final_kernel(const double* __restrict__ k2out, const float* __restrict__ saArr,
                             float* __restrict__ out)
{
    __shared__ double red[4][4];
    const int t = threadIdx.x;
    double d = 0.0, f2 = 0.0, sf = 0.0, sr = 0.0;
    if (t < NFREQ) { d = k2out[2 * t]; f2 = k2out[2 * t + 1]; }
    for (int i = t; i < GRP; i += 256) {
        sf += (double)saArr[i];
        sr += (double)saArr[GRP + i];
    }
    #pragma unroll
    for (int off = 32; off; off >>= 1) {
        d  += __shfl_down(d,  off, 64);
        f2 += __shfl_down(f2, off, 64);
        sf += __shfl_down(sf, off, 64);
        sr += __shfl_down(sr, off, 64);
    }
    const int w = t >> 6;
    if ((t & 63) == 0) { red[0][w] = d; red[1][w] = f2; red[2][w] = sf; red[3][w] = sr; }
    __syncthreads();
    if (t == 0) {
        double D  = red[0][0] + red[0][1] + red[0][2] + red[0][3];
        double FF = red[1][0] + red[1][1] + red[1][2] + red[1][3];
        double SF = red[2][0] + red[2][1] + red[2][2] + red[2][3];
        double SR = red[3][0] + red[3][1] + red[3][2] + red[3][3];

        const double n    = (double)NELEM;
        const double nseg = (double)NSEG;
        const double m    = nseg * (nseg - 1.0) * 0.5;

        out[0] = (float)((SF / nseg + SR / nseg - 2.0 * D / (nseg * nseg)) / n);
        out[1] = (float)((nseg * SF - FF) / (n * m));
    }
}

extern "C" void kernel_launch(void* const* d_in, const int* in_sizes, int n_in,
                              void* d_out, int out_size, void* d_ws, size_t ws_size,
                              hipStream_t stream) {
    const float* fake = (const float*)d_in[0];
    const float* real = (const float*)d_in[1];
    float* ws  = (float*)d_ws;
    float* out = (float*)d_out;

    // ws layout (floats): part[800*13056] | saArr[800] | pb[2*NJ*13056] | k2out (doubles)
    const size_t SA_FL = (size_t)NBLK * NELEM;            // 10,444,800
    const size_t PB_FL = SA_FL + NBLK;                    // +800
    const size_t K2_BY = (PB_FL + (size_t)2 * NJ * NELEM) * 4;  // byte offset, 8B-aligned

    float*  sa = ws + SA_FL;
    float*  pb = ws + PB_FL;
    double* k2 = (double*)((char*)d_ws + K2_BY);

    psd_seg_kernel<<<NBLK, 256, 0, stream>>>(fake, real, ws, sa);
    reduce_part_kernel<<<dim3(NFREQ, NJ), 256, 0, stream>>>(ws, pb);
    dot_kernel<<<NFREQ, 256, 0, stream>>>(pb, k2);
    final_kernel<<<1, 256, 0, stream>>>(k2, sa, out);
}